// Round 1
// baseline (986.341 us; speedup 1.0000x reference)
//
#include <hip/hip_runtime.h>

#define NN 50000
#define EE 800000
#define HD 64

// order-preserving float->uint key for atomicMax-based segment max.
// memset-0 init is below any finite key (min finite key = 0x00800000).
__device__ __forceinline__ unsigned fkey(float f) {
    unsigned b = __float_as_uint(f);
    return (b & 0x80000000u) ? ~b : (b | 0x80000000u);
}
__device__ __forceinline__ float fdecode(unsigned k) {
    unsigned b = (k & 0x80000000u) ? (k & 0x7FFFFFFFu) : ~k;
    return __uint_as_float(b);
}

// K1: per-node fused transform.
// z = h@fcW ; zi = h@fcU ; v = tanh(pot@Wpot + bpot)
// zs = z . a[0:64] ; zd = z . a[64:128] ; base = gate * v * zi
__global__ __launch_bounds__(256) void node_transform(
    const float* __restrict__ hin, const float* __restrict__ pot,
    const float* __restrict__ Wpot, const float* __restrict__ bpot,
    const float* __restrict__ fcW, const float* __restrict__ fcU,
    const float* __restrict__ a, const float* __restrict__ gate,
    float* __restrict__ z, float* __restrict__ zs, float* __restrict__ zd,
    float* __restrict__ base)
{
    __shared__ float sW[64 * 64];
    __shared__ float sU[64 * 64];
    __shared__ float sP[16 * 64];
    __shared__ float sb[64], sg[64], sas[64], sad[64];
    for (int i = threadIdx.x; i < 64 * 64; i += 256) { sW[i] = fcW[i]; sU[i] = fcU[i]; }
    for (int i = threadIdx.x; i < 16 * 64; i += 256) sP[i] = Wpot[i];
    if (threadIdx.x < 64) {
        sb[threadIdx.x]  = bpot[threadIdx.x];
        sg[threadIdx.x]  = gate[threadIdx.x];
        sas[threadIdx.x] = a[threadIdx.x];
        sad[threadIdx.x] = a[64 + threadIdx.x];
    }
    __syncthreads();

    const int lane   = threadIdx.x & 63;
    const int wave   = blockIdx.x * 4 + (threadIdx.x >> 6);
    const int nwaves = gridDim.x * 4;

    for (int n = wave; n < NN; n += nwaves) {
        float h = hin[n * 64 + lane];
        float p = (lane < 16) ? pot[n * 16 + lane] : 0.f;
        float zj = 0.f, zij = 0.f;
#pragma unroll
        for (int k = 0; k < 64; k++) {
            float hk = __shfl(h, k);
            zj  += hk * sW[k * 64 + lane];
            zij += hk * sU[k * 64 + lane];
        }
        float vj = sb[lane];
#pragma unroll
        for (int k = 0; k < 16; k++) {
            vj += __shfl(p, k) * sP[k * 64 + lane];
        }
        vj = tanhf(vj);

        float rs = zj * sas[lane];
        float rd = zj * sad[lane];
#pragma unroll
        for (int off = 32; off; off >>= 1) {
            rs += __shfl_xor(rs, off);
            rd += __shfl_xor(rd, off);
        }
        z[n * 64 + lane]    = zj;
        base[n * 64 + lane] = sg[lane] * vj * zij;
        if (lane == 0) { zs[n] = rs; zd[n] = rd; }
    }
}

// K2: per-edge score + segment-max (atomicMax on uint keys).
__global__ __launch_bounds__(256) void edge_score(
    const float* __restrict__ et, const int* __restrict__ src, const int* __restrict__ dst,
    const float* __restrict__ a, const float* __restrict__ zs, const float* __restrict__ zd,
    float* __restrict__ score, unsigned* __restrict__ mkeys)
{
    const int lane   = threadIdx.x & 63;
    const float at   = a[128 + lane];
    const int wave   = blockIdx.x * 4 + (threadIdx.x >> 6);
    const int nwaves = gridDim.x * 4;

    for (int e = wave; e < EE; e += nwaves) {
        float r = et[(size_t)e * 64 + lane] * at;
#pragma unroll
        for (int off = 32; off; off >>= 1) r += __shfl_xor(r, off);
        if (lane == 0) {
            int s = src[e], d = dst[e];
            float sc = zs[s] + zd[d] + r;
            sc = (sc >= 0.f) ? sc : 0.01f * sc;
            score[e] = sc;
            atomicMax(mkeys + d, fkey(sc));
        }
    }
}

// K3: per-edge exp + scatter-accumulate (fp32 atomics).
__global__ __launch_bounds__(256) void edge_accum(
    const int* __restrict__ src, const int* __restrict__ dst,
    const float* __restrict__ score, const unsigned* __restrict__ mkeys,
    const float* __restrict__ z, float* __restrict__ denom, float* __restrict__ accum)
{
    const int lane   = threadIdx.x & 63;
    const int wave   = blockIdx.x * 4 + (threadIdx.x >> 6);
    const int nwaves = gridDim.x * 4;

    for (int e = wave; e < EE; e += nwaves) {
        int s = src[e], d = dst[e];
        float m  = fdecode(mkeys[d]);
        float ex = __expf(score[e] - m);
        float zv = z[s * 64 + lane];
        atomicAdd(accum + (size_t)d * 64 + lane, ex * zv);
        if (lane == 0) atomicAdd(denom + d, ex);
    }
}

// K4: out = accum / denom' + base  (denom'==1 when denom==0)
__global__ __launch_bounds__(256) void node_final(
    const float* __restrict__ accum, const float* __restrict__ denom,
    const float* __restrict__ base, float* __restrict__ out)
{
    int i = blockIdx.x * 256 + threadIdx.x;
    if (i >= NN * 64) return;
    int n = i >> 6;
    float d = denom[n];
    d = (d == 0.f) ? 1.f : d;
    out[i] = accum[i] / d + base[i];
}

extern "C" void kernel_launch(void* const* d_in, const int* in_sizes, int n_in,
                              void* d_out, int out_size, void* d_ws, size_t ws_size,
                              hipStream_t stream)
{
    const float* attr  = (const float*)d_in[0];
    const float* pot0  = (const float*)d_in[1];
    const float* pot1  = (const float*)d_in[2];
    const float* et0   = (const float*)d_in[3];
    const float* et1   = (const float*)d_in[4];
    const float* Wpot  = (const float*)d_in[5];
    const float* bpot  = (const float*)d_in[6];
    const float* fcW0  = (const float*)d_in[7];
    const float* fcU0  = (const float*)d_in[8];
    const float* a0    = (const float*)d_in[9];
    const float* gate0 = (const float*)d_in[10];
    const float* fcW1  = (const float*)d_in[11];
    const float* fcU1  = (const float*)d_in[12];
    const float* a1    = (const float*)d_in[13];
    const float* gate1 = (const float*)d_in[14];
    const int*   src   = (const int*)d_in[15];
    const int*   dst   = (const int*)d_in[16];

    float* out = (float*)d_out;

    float* ws = (float*)d_ws;
    float* z     = ws;                  // NN*64
    float* base  = z + NN * 64;         // NN*64
    float* h1    = base + NN * 64;      // NN*64 (layer-0 output, also its accum)
    float* zs    = h1 + NN * 64;        // NN
    float* zd    = zs + NN;             // NN
    float* score = zd + NN;             // EE
    float* denom = score + EE;          // NN
    unsigned* mkeys = (unsigned*)(denom + NN); // NN

    const int nfin = (NN * 64 + 255) / 256;

    // ---------------- layer 0 ----------------
    hipMemsetAsync(mkeys, 0, NN * sizeof(unsigned), stream);
    hipMemsetAsync(denom, 0, NN * sizeof(float), stream);
    hipMemsetAsync(h1, 0, (size_t)NN * 64 * sizeof(float), stream);
    node_transform<<<1024, 256, 0, stream>>>(attr, pot0, Wpot, bpot, fcW0, fcU0,
                                             a0, gate0, z, zs, zd, base);
    edge_score<<<4096, 256, 0, stream>>>(et0, src, dst, a0, zs, zd, score, mkeys);
    edge_accum<<<4096, 256, 0, stream>>>(src, dst, score, mkeys, z, denom, h1);
    node_final<<<nfin, 256, 0, stream>>>(h1, denom, base, h1);

    // ---------------- layer 1 ----------------
    hipMemsetAsync(mkeys, 0, NN * sizeof(unsigned), stream);
    hipMemsetAsync(denom, 0, NN * sizeof(float), stream);
    hipMemsetAsync(out, 0, (size_t)NN * 64 * sizeof(float), stream);
    node_transform<<<1024, 256, 0, stream>>>(h1, pot1, Wpot, bpot, fcW1, fcU1,
                                             a1, gate1, z, zs, zd, base);
    edge_score<<<4096, 256, 0, stream>>>(et1, src, dst, a1, zs, zd, score, mkeys);
    edge_accum<<<4096, 256, 0, stream>>>(src, dst, score, mkeys, z, denom, out);
    node_final<<<nfin, 256, 0, stream>>>(out, denom, base, out);
}

// Round 2
// 562.343 us; speedup vs baseline: 1.7540x; 1.7540x over previous
//
#include <hip/hip_runtime.h>
#include <math.h>

#define NN 50000
#define EE 800000

// ---------------- CSR build ----------------

__global__ __launch_bounds__(256) void k_hist(const int* __restrict__ dst, int* __restrict__ deg) {
    int e = blockIdx.x * 256 + threadIdx.x;
    if (e < EE) atomicAdd(&deg[dst[e]], 1);
}

// single-block exclusive scan of deg[0..NN) -> rowptr; deg becomes pos (= rowptr copy)
__global__ __launch_bounds__(1024) void k_scan(int* __restrict__ deg, int* __restrict__ rowptr) {
    __shared__ int part[1024];
    const int t  = threadIdx.x;
    const int CH = (NN + 1023) / 1024;
    const int b  = t * CH;
    const int e  = min(b + CH, NN);
    int sum = 0;
    for (int i = b; i < e; i++) sum += deg[i];
    part[t] = sum;
    __syncthreads();
    for (int off = 1; off < 1024; off <<= 1) {
        int v = (t >= off) ? part[t - off] : 0;
        __syncthreads();
        part[t] += v;
        __syncthreads();
    }
    int run = (t == 0) ? 0 : part[t - 1];
    for (int i = b; i < e; i++) {
        int d = deg[i];
        rowptr[i] = run;
        deg[i]    = run;   // pos
        run += d;
    }
    if (t == 0) rowptr[NN] = EE;
}

__global__ __launch_bounds__(256) void k_scatter(const int* __restrict__ src, const int* __restrict__ dst,
                                                 int* __restrict__ pos, int* __restrict__ eidx,
                                                 int* __restrict__ esrc) {
    int e = blockIdx.x * 256 + threadIdx.x;
    if (e < EE) {
        int d = dst[e];
        int p = atomicAdd(&pos[d], 1);
        eidx[p] = e;
        esrc[p] = src[e];
    }
}

// ---------------- per-layer kernels ----------------

// K1: per-node fused transform.
__global__ __launch_bounds__(256) void node_transform(
    const float* __restrict__ hin, const float* __restrict__ pot,
    const float* __restrict__ Wpot, const float* __restrict__ bpot,
    const float* __restrict__ fcW, const float* __restrict__ fcU,
    const float* __restrict__ a, const float* __restrict__ gate,
    float* __restrict__ z, float* __restrict__ zs, float* __restrict__ zd,
    float* __restrict__ base)
{
    __shared__ float sW[64 * 64];
    __shared__ float sU[64 * 64];
    __shared__ float sP[16 * 64];
    __shared__ float sb[64], sg[64], sas[64], sad[64];
    for (int i = threadIdx.x; i < 64 * 64; i += 256) { sW[i] = fcW[i]; sU[i] = fcU[i]; }
    for (int i = threadIdx.x; i < 16 * 64; i += 256) sP[i] = Wpot[i];
    if (threadIdx.x < 64) {
        sb[threadIdx.x]  = bpot[threadIdx.x];
        sg[threadIdx.x]  = gate[threadIdx.x];
        sas[threadIdx.x] = a[threadIdx.x];
        sad[threadIdx.x] = a[64 + threadIdx.x];
    }
    __syncthreads();

    const int lane   = threadIdx.x & 63;
    const int wave   = blockIdx.x * 4 + (threadIdx.x >> 6);
    const int nwaves = gridDim.x * 4;

    for (int n = wave; n < NN; n += nwaves) {
        float h = hin[n * 64 + lane];
        float p = (lane < 16) ? pot[n * 16 + lane] : 0.f;
        float zj = 0.f, zij = 0.f;
#pragma unroll
        for (int k = 0; k < 64; k++) {
            float hk = __shfl(h, k);
            zj  += hk * sW[k * 64 + lane];
            zij += hk * sU[k * 64 + lane];
        }
        float vj = sb[lane];
#pragma unroll
        for (int k = 0; k < 16; k++) vj += __shfl(p, k) * sP[k * 64 + lane];
        vj = tanhf(vj);

        float rs = zj * sas[lane];
        float rd = zj * sad[lane];
#pragma unroll
        for (int off = 32; off; off >>= 1) {
            rs += __shfl_xor(rs, off);
            rd += __shfl_xor(rd, off);
        }
        z[n * 64 + lane]    = zj;
        base[n * 64 + lane] = sg[lane] * vj * zij;
        if (lane == 0) { zs[n] = rs; zd[n] = rd; }
    }
}

// K2: streaming dot  score_t[e] = et[e,:] . a_t   (float4, 16 lanes/edge)
__global__ __launch_bounds__(256) void edge_dot(
    const float* __restrict__ et, const float* __restrict__ a,
    float* __restrict__ score_t)
{
    const int gid    = blockIdx.x * 256 + threadIdx.x;
    const int stride = gridDim.x * 256;          // multiple of 16
    const int p      = gid & 15;
    const float4 at4 = *reinterpret_cast<const float4*>(a + 128 + p * 4);
    const float4* et4 = reinterpret_cast<const float4*>(et);
    const int lane = threadIdx.x & 63;

    for (int i = gid; i < EE * 16; i += stride) {
        float4 v = et4[i];
        float r = v.x * at4.x + v.y * at4.y + v.z * at4.z + v.w * at4.w;
        r += __shfl_xor(r, 8);
        r += __shfl_xor(r, 4);
        r += __shfl_xor(r, 2);
        r += __shfl_xor(r, 1);
        if ((lane & 15) == 0) score_t[i >> 4] = r;
    }
}

// K3: wave per dst node -- score assemble + leaky_relu + segment softmax.
// writes ex into csr_sc[j] (CSR order) and 1/denom into rden[n].
__global__ __launch_bounds__(256) void node_softmax(
    const int* __restrict__ rowptr, const int* __restrict__ eidx, const int* __restrict__ esrc,
    const float* __restrict__ score_t, const float* __restrict__ zs, const float* __restrict__ zd,
    float* __restrict__ csr_sc, float* __restrict__ rden)
{
    const int lane = threadIdx.x & 63;
    const int n    = blockIdx.x * 4 + (threadIdx.x >> 6);
    if (n >= NN) return;

    const int s0 = rowptr[n], s1 = rowptr[n + 1];
    const int deg = s1 - s0;
    const float zdn = zd[n];

    if (deg <= 64) {
        const int j = s0 + lane;
        float sc = -INFINITY;
        if (j < s1) {
            int e = eidx[j], s = esrc[j];
            float v = score_t[e] + zs[s] + zdn;
            sc = (v >= 0.f) ? v : 0.01f * v;
        }
        float mx = sc;
#pragma unroll
        for (int off = 32; off; off >>= 1) mx = fmaxf(mx, __shfl_xor(mx, off));
        float ex = (j < s1) ? __expf(sc - mx) : 0.f;
        float ds = ex;
#pragma unroll
        for (int off = 32; off; off >>= 1) ds += __shfl_xor(ds, off);
        if (j < s1) csr_sc[j] = ex;
        if (lane == 0) rden[n] = 1.f / ((ds == 0.f) ? 1.f : ds);
    } else {
        float mx = -INFINITY;
        for (int j = s0 + lane; j < s1; j += 64) {
            int e = eidx[j], s = esrc[j];
            float v = score_t[e] + zs[s] + zdn;
            v = (v >= 0.f) ? v : 0.01f * v;
            csr_sc[j] = v;
            mx = fmaxf(mx, v);
        }
#pragma unroll
        for (int off = 32; off; off >>= 1) mx = fmaxf(mx, __shfl_xor(mx, off));
        float ds = 0.f;
        for (int j = s0 + lane; j < s1; j += 64) {
            float ex = __expf(csr_sc[j] - mx);
            csr_sc[j] = ex;
            ds += ex;
        }
#pragma unroll
        for (int off = 32; off; off >>= 1) ds += __shfl_xor(ds, off);
        if (lane == 0) rden[n] = 1.f / ((ds == 0.f) ? 1.f : ds);
    }
}

// K4: wave per dst node -- out[n] = (sum_j ex_j * z[src_j]) * rden[n] + base[n]
__global__ __launch_bounds__(256) void node_aggregate(
    const int* __restrict__ rowptr, const int* __restrict__ esrc,
    const float* __restrict__ csr_sc, const float* __restrict__ rden,
    const float* __restrict__ z, const float* __restrict__ base,
    float* __restrict__ out)
{
    const int lane = threadIdx.x & 63;
    const int n    = blockIdx.x * 4 + (threadIdx.x >> 6);
    if (n >= NN) return;

    const int s0 = rowptr[n], s1 = rowptr[n + 1];
    const int deg = s1 - s0;

    const int j   = s0 + lane;
    int   sv  = (j < s1) ? esrc[j]   : 0;
    float exv = (j < s1) ? csr_sc[j] : 0.f;

    float acc = 0.f;
    const int cnt = (deg < 64) ? deg : 64;
    for (int t = 0; t < cnt; t++) {
        int   s  = __shfl(sv, t);
        float ex = __shfl(exv, t);
        acc = fmaf(ex, z[(size_t)s * 64 + lane], acc);
    }
    for (int jj = s0 + 64; jj < s1; jj++) {      // deg > 64 tail (rare)
        int   s  = esrc[jj];
        float ex = csr_sc[jj];
        acc = fmaf(ex, z[(size_t)s * 64 + lane], acc);
    }
    const size_t o = (size_t)n * 64 + lane;
    out[o] = acc * rden[n] + base[o];
}

// ---------------- launch ----------------

extern "C" void kernel_launch(void* const* d_in, const int* in_sizes, int n_in,
                              void* d_out, int out_size, void* d_ws, size_t ws_size,
                              hipStream_t stream)
{
    const float* attr  = (const float*)d_in[0];
    const float* pot0  = (const float*)d_in[1];
    const float* pot1  = (const float*)d_in[2];
    const float* et0   = (const float*)d_in[3];
    const float* et1   = (const float*)d_in[4];
    const float* Wpot  = (const float*)d_in[5];
    const float* bpot  = (const float*)d_in[6];
    const float* fcW0  = (const float*)d_in[7];
    const float* fcU0  = (const float*)d_in[8];
    const float* a0    = (const float*)d_in[9];
    const float* gate0 = (const float*)d_in[10];
    const float* fcW1  = (const float*)d_in[11];
    const float* fcU1  = (const float*)d_in[12];
    const float* a1    = (const float*)d_in[13];
    const float* gate1 = (const float*)d_in[14];
    const int*   src   = (const int*)d_in[15];
    const int*   dst   = (const int*)d_in[16];

    float* out = (float*)d_out;

    // workspace layout
    float* ws      = (float*)d_ws;
    float* z       = ws;                    // NN*64
    float* base    = z + NN * 64;           // NN*64
    float* zs      = base + NN * 64;        // NN
    float* zd      = zs + NN;               // NN
    float* rden    = zd + NN;               // NN
    float* score_t = rden + NN;             // EE
    float* csr_sc  = score_t + EE;          // EE
    int*   rowptr  = (int*)(csr_sc + EE);   // NN+1
    int*   deg     = rowptr + NN + 1;       // NN (becomes pos)
    int*   eidx    = deg + NN;              // EE
    int*   esrc    = eidx + EE;             // EE

    const int eblk = (EE + 255) / 256;
    const int nblk = (NN + 3) / 4;

    // CSR build (shared by both layers)
    hipMemsetAsync(deg, 0, NN * sizeof(int), stream);
    k_hist<<<eblk, 256, 0, stream>>>(dst, deg);
    k_scan<<<1, 1024, 0, stream>>>(deg, rowptr);
    k_scatter<<<eblk, 256, 0, stream>>>(src, dst, deg, eidx, esrc);

    // ---------------- layer 0 ----------------
    node_transform<<<1024, 256, 0, stream>>>(attr, pot0, Wpot, bpot, fcW0, fcU0,
                                             a0, gate0, z, zs, zd, base);
    edge_dot<<<2048, 256, 0, stream>>>(et0, a0, score_t);
    node_softmax<<<nblk, 256, 0, stream>>>(rowptr, eidx, esrc, score_t, zs, zd, csr_sc, rden);
    node_aggregate<<<nblk, 256, 0, stream>>>(rowptr, esrc, csr_sc, rden, z, base, out);

    // ---------------- layer 1 ---------------- (h = out from layer 0)
    node_transform<<<1024, 256, 0, stream>>>(out, pot1, Wpot, bpot, fcW1, fcU1,
                                             a1, gate1, z, zs, zd, base);
    edge_dot<<<2048, 256, 0, stream>>>(et1, a1, score_t);
    node_softmax<<<nblk, 256, 0, stream>>>(rowptr, eidx, esrc, score_t, zs, zd, csr_sc, rden);
    node_aggregate<<<nblk, 256, 0, stream>>>(rowptr, esrc, csr_sc, rden, z, base, out);
}